// Round 10
// baseline (298.415 us; speedup 1.0000x reference)
//
#include <hip/hip_runtime.h>
#include <hip/hip_bf16.h>
#include <cstdint>

// B=512, D=256, H=512. out: [512,512] fp32.
// ws: Ai [512*512] f32 (pre-scaled C2) | Aj [512*512] f32 ((..+b1)*C2) | W2q [512*512] i8 swizzled

#define NB 512
#define ND 256
#define NH 512
#define C2 2.885390081777927f  // 2*log2(e): tanh(x) = 1 - 2/(exp2(x*C2)+1)

typedef int i32x4 __attribute__((ext_vector_type(4)));
typedef int i32x16 __attribute__((ext_vector_type(16)));
typedef unsigned int u32;
typedef unsigned char u8;

__device__ __forceinline__ float exp2_fast(float x) {
#if __has_builtin(__builtin_amdgcn_exp2f)
  return __builtin_amdgcn_exp2f(x);
#else
  return exp2f(x);
#endif
}
__device__ __forceinline__ float rcp_fast(float x) {
#if __has_builtin(__builtin_amdgcn_rcpf)
  return __builtin_amdgcn_rcpf(x);
#else
  return 1.0f / x;
#endif
}
__device__ __forceinline__ u32 perm_b32(u32 hi, u32 lo, u32 sel) {
#if __has_builtin(__builtin_amdgcn_perm)
  return __builtin_amdgcn_perm(hi, lo, sel);
#else
  u32 r = 0;
  for (int b = 0; b < 4; ++b) {
    const u32 c = (sel >> (8 * b)) & 255;
    const u32 byte = (c < 4) ? (lo >> (8 * c)) & 255 : (c < 8) ? (hi >> (8 * (c - 4))) & 255 : 0;
    r |= byte << (8 * b);
  }
  return r;
#endif
}
// u pre-scaled by C2: float whose low byte = int8(round(127*tanh(u/C2)))  (trans pipe: exp2+rcp)
__device__ __forceinline__ u32 tanh_q127_magic(float u) {
  const float r = rcp_fast(exp2_fast(u) + 1.0f);
  // 12583039 = 1.5*2^23 + 127; result = MAGIC + (127 - 254 r), RNE in the fma; low byte = i8.
  return __builtin_bit_cast(u32, fmaf(-254.0f, r, 12583039.0f));
}

// ---------------- prep: blocks 0..1023 Ai/Aj GEMM (1 i-row, n-half); 1024..1087 W2 -> i8 ----------------
__global__ __launch_bounds__(256) void prep_all(const float* __restrict__ h,
                                                const float* __restrict__ W1,
                                                const float* __restrict__ b1,
                                                const float* __restrict__ W2,
                                                float* __restrict__ Ai,
                                                float* __restrict__ Aj,
                                                u8* __restrict__ W2q) {
  const int t = threadIdx.x;
  const int bx = blockIdx.x;
  if (bx < 1024) {
    __shared__ float hsh[ND];
    const int i = bx >> 1;
    const int n = (bx & 1) * 256 + t;
    hsh[t] = h[i * ND + t];
    __syncthreads();
    float ai = 0.0f, aj = 0.0f;
#pragma unroll 8
    for (int d = 0; d < ND; ++d) {
      const float hd = hsh[d];
      ai = fmaf(hd, W1[d * NH + n], ai);
      aj = fmaf(hd, W1[(d + ND) * NH + n], aj);
    }
    Ai[i * NH + n] = ai * C2;
    Aj[i * NH + n] = (aj + b1[n]) * C2;
  } else {
    // W2 -> i8 (scale 0.25/127), MFMA B-frag order for i8 32x32x32:
    // frag id g = ks*1024 + nt*64 + lane (16 B): byte j = q(W2[ks*32 + (lane>>5)*16 + j][nt*32 + (lane&31)])
    const int g = (bx - 1024) * 256 + t;  // 0..16383
    const int lane = g & 63;
    const int nt = (g >> 6) & 15;
    const int ks = g >> 10;
    const int n = nt * 32 + (lane & 31);
    const int kb = ks * 32 + ((lane >> 5) << 4);
    u32 w[4];
#pragma unroll
    for (int q = 0; q < 4; ++q) {
      u32 acc = 0;
#pragma unroll
      for (int j = 0; j < 4; ++j) {
        const float wv = fminf(fmaxf(W2[(kb + q * 4 + j) * NH + n], -0.25f), 0.25f);
        const int qi = (int)rintf(wv * 508.0f);  // 508 = 127/0.25
        acc |= ((u32)(qi & 255)) << (8 * j);
      }
      w[q] = acc;
    }
    ((uint4*)W2q)[g] = make_uint4(w[0], w[1], w[2], w[3]);
  }
}

// ---------------- main: i8 pairwise tanh-MLP; M=64 tile, 1024 thr / 16 waves, acc=32/lane ----------------
// Block: one i, 64 j's (M=64), N=512, K=512 (16 ks-steps of 32).
// Wave w: mt = w&1 (M-half of 32 rows), ng = w>>1 (2 n-tiles nt = ng*2+{0,1}).
// X LDS: 16-B slot idx = s*64 + row, s = k>>4; byte j of slot = i8(127*tanh(X[row][s*16+j])).
// A frag (ks): i32x4 at idx ks*128 + (lane>>5)*64 + mt*32 + (lane&31).
// B frag (ks,ntl): uint4 at W2q frag id ks*1024 + (ng*2+ntl)*64 + lane.
// K-loop: ping-pong x2 unroll, SSA register sets, prefetch distance 2, no barriers.
__global__ __launch_bounds__(1024, 2) void pair_main(const float* __restrict__ Ai,
                                                     const float* __restrict__ Aj,
                                                     const u8* __restrict__ W2q,
                                                     const float* __restrict__ b2,
                                                     const float* __restrict__ W3,
                                                     const float* __restrict__ b3,
                                                     float* __restrict__ out) {
  __shared__ __align__(16) u8 xs[64 * 512];  // 32 KB
  __shared__ float red[16][32];              // 2 KB

  const int t = threadIdx.x;
  const int w = t >> 6;
  const int lane = t & 63;
  const int lhi = lane >> 5;
  const int llo = lane & 31;
  const int mt = w & 1;
  const int ng = w >> 1;
  const int bx = blockIdx.x;
  const int i = bx >> 3;
  const int j0 = (bx & 7) * 64;

  i32x16 acc[2];
#pragma unroll
  for (int nt = 0; nt < 2; ++nt)
#pragma unroll
    for (int q = 0; q < 16; ++q) acc[nt][q] = 0;

  // ---- stage X: thread t -> row = t&63, slots s in {t>>6, (t>>6)+16} (16 k's each) ----
  {
    const int row = t & 63;
    const int s0 = t >> 6;  // 0..15
    const float* ajr = Aj + (size_t)(j0 + row) * NH;
    const float* air = Ai + (size_t)i * NH;
#pragma unroll
    for (int uu = 0; uu < 2; ++uu) {
      const int s = s0 + uu * 16;
      const int k0 = s * 16;
      u32 wds[4];
#pragma unroll
      for (int q = 0; q < 4; ++q) {
        const float4 fa = *(const float4*)(ajr + k0 + q * 4);
        const float4 ga = *(const float4*)(air + k0 + q * 4);
        const u32 m0 = tanh_q127_magic(fa.x + ga.x);
        const u32 m1 = tanh_q127_magic(fa.y + ga.y);
        const u32 m2 = tanh_q127_magic(fa.z + ga.z);
        const u32 m3 = tanh_q127_magic(fa.w + ga.w);
        const u32 p01 = perm_b32(m1, m0, 0x0C0C0400u);
        const u32 p23 = perm_b32(m3, m2, 0x0C0C0400u);
        wds[q] = perm_b32(p23, p01, 0x05040100u);
      }
      ((uint4*)xs)[s * 64 + row] = make_uint4(wds[0], wds[1], wds[2], wds[3]);
    }
  }
  __syncthreads();  // only block-wide barrier before epilogue

  // ---- K-loop ----
  const i32x4* xsv = (const i32x4*)xs;
  const int abase = lhi * 64 + mt * 32 + llo;              // + ks*128
  const uint4* w2v = (const uint4*)W2q + ng * 128 + lane;  // + ks*1024, +64 for ntl=1

  i32x4 aP0 = xsv[abase];
  i32x4 aP1 = xsv[128 + abase];
  uint4 bP00 = w2v[0], bP01 = w2v[64];
  uint4 bP10 = w2v[1024], bP11 = w2v[1024 + 64];

#pragma unroll
  for (int kk = 0; kk < 8; ++kk) {
    const int ks0 = 2 * kk;
    {
      const i32x4 a = aP0;
      const i32x4 c0 = __builtin_bit_cast(i32x4, bP00);
      const i32x4 c1 = __builtin_bit_cast(i32x4, bP01);
      if (kk < 7) {
        aP0 = xsv[(ks0 + 2) * 128 + abase];
        const uint4* wp = w2v + (ks0 + 2) * 1024;
        bP00 = wp[0];
        bP01 = wp[64];
      }
      acc[0] = __builtin_amdgcn_mfma_i32_32x32x32_i8(a, c0, acc[0], 0, 0, 0);
      acc[1] = __builtin_amdgcn_mfma_i32_32x32x32_i8(a, c1, acc[1], 0, 0, 0);
    }
    {
      const i32x4 a = aP1;
      const i32x4 c0 = __builtin_bit_cast(i32x4, bP10);
      const i32x4 c1 = __builtin_bit_cast(i32x4, bP11);
      if (kk < 7) {
        aP1 = xsv[(ks0 + 3) * 128 + abase];
        const uint4* wp = w2v + (ks0 + 3) * 1024;
        bP10 = wp[0];
        bP11 = wp[64];
      }
      acc[0] = __builtin_amdgcn_mfma_i32_32x32x32_i8(a, c0, acc[0], 0, 0, 0);
      acc[1] = __builtin_amdgcn_mfma_i32_32x32x32_i8(a, c1, acc[1], 0, 0, 0);
    }
  }

  // ---- epilogue: y = acc*SCALE + b2*C2; r = 1/(exp2(y)+1); partial = Σw3 - 2 Σ w3·r ----
  const float SCALE = (0.25f / (127.0f * 127.0f)) * C2;
  float b2c[2], w3v[2];
#pragma unroll
  for (int ntl = 0; ntl < 2; ++ntl) {
    const int n = ng * 64 + ntl * 32 + llo;
    b2c[ntl] = b2[n] * C2;
    w3v[ntl] = W3[n];
  }
  float w3s = w3v[0] + w3v[1];
#pragma unroll
  for (int off = 1; off < 32; off <<= 1) w3s += __shfl_xor(w3s, off, 64);  // Σ w3 over wave's 64 n

#pragma unroll
  for (int reg = 0; reg < 16; ++reg) {
    float sr = 0.0f;
#pragma unroll
    for (int ntl = 0; ntl < 2; ++ntl) {
      const float y = fmaf((float)acc[ntl][reg], SCALE, b2c[ntl]);
      const float r = rcp_fast(exp2_fast(y) + 1.0f);
      sr = fmaf(w3v[ntl], r, sr);
    }
#pragma unroll
    for (int off = 1; off < 32; off <<= 1) sr += __shfl_xor(sr, off, 64);
    const int row = (reg & 3) + 8 * (reg >> 2) + 4 * lhi;  // 0..31 within M-half
    if (llo == reg) red[w][row] = fmaf(-2.0f, sr, w3s);
  }
  __syncthreads();
  if (t < 64) {
    const int mtf = t >> 5;  // which M-half
    const int rr = t & 31;
    float v = b3[0];
#pragma unroll
    for (int g = 0; g < 8; ++g) v += red[g * 2 + mtf][rr];
    const int j = j0 + t;
    out[i * NB + j] = (j == i) ? -20.0f : v;
  }
}

extern "C" void kernel_launch(void* const* d_in, const int* in_sizes, int n_in,
                              void* d_out, int out_size, void* d_ws, size_t ws_size,
                              hipStream_t stream) {
  const float* h = (const float*)d_in[0];
  const float* W1 = (const float*)d_in[1];
  const float* b1 = (const float*)d_in[2];
  const float* W2 = (const float*)d_in[3];
  const float* b2 = (const float*)d_in[4];
  const float* W3 = (const float*)d_in[5];
  const float* b3 = (const float*)d_in[6];
  float* out = (float*)d_out;

  float* Ai = (float*)d_ws;
  float* Aj = Ai + NB * NH;
  u8* W2q = (u8*)(Aj + NB * NH);

  prep_all<<<1088, 256, 0, stream>>>(h, W1, b1, W2, Ai, Aj, W2q);
  pair_main<<<4096, 1024, 0, stream>>>(Ai, Aj, W2q, b2, W3, b3, out);
}

// Round 12
// 237.083 us; speedup vs baseline: 1.2587x; 1.2587x over previous
//
#include <hip/hip_runtime.h>
#include <hip/hip_bf16.h>
#include <cstdint>

// B=512, D=256, H=512. out: [512,512] fp32.
// ws: Ai [512*512] f32 (pre-scaled C2) | Aj [512*512] f32 ((..+b1)*C2) | W2q [512*512] i8 swizzled

#define NB 512
#define ND 256
#define NH 512
#define C2 2.885390081777927f  // 2*log2(e): tanh(x) = 1 - 2/(exp2(x*C2)+1)

typedef int i32x4 __attribute__((ext_vector_type(4)));
typedef int i32x16 __attribute__((ext_vector_type(16)));
typedef unsigned int u32;
typedef unsigned char u8;

__device__ __forceinline__ float exp2_fast(float x) {
#if __has_builtin(__builtin_amdgcn_exp2f)
  return __builtin_amdgcn_exp2f(x);
#else
  return exp2f(x);
#endif
}
__device__ __forceinline__ float rcp_fast(float x) {
#if __has_builtin(__builtin_amdgcn_rcpf)
  return __builtin_amdgcn_rcpf(x);
#else
  return 1.0f / x;
#endif
}
__device__ __forceinline__ u32 perm_b32(u32 hi, u32 lo, u32 sel) {
#if __has_builtin(__builtin_amdgcn_perm)
  return __builtin_amdgcn_perm(hi, lo, sel);
#else
  u32 r = 0;
  for (int b = 0; b < 4; ++b) {
    const u32 c = (sel >> (8 * b)) & 255;
    const u32 byte = (c < 4) ? (lo >> (8 * c)) & 255 : (c < 8) ? (hi >> (8 * (c - 4))) & 255 : 0;
    r |= byte << (8 * b);
  }
  return r;
#endif
}
// u pre-scaled by C2: float whose low byte = int8(round(127*tanh(u/C2)))  (trans pipe: exp2+rcp)
__device__ __forceinline__ u32 tanh_q127_magic(float u) {
  const float r = rcp_fast(exp2_fast(u) + 1.0f);
  // 12583039 = 1.5*2^23 + 127; result = MAGIC + (127 - 254 r), RNE in the fma; low byte = i8.
  return __builtin_bit_cast(u32, fmaf(-254.0f, r, 12583039.0f));
}

// ---------------- prep: blocks 0..1023 Ai/Aj GEMM (1 i-row, n-half); 1024..1087 W2 -> i8 ----------------
__global__ __launch_bounds__(256) void prep_all(const float* __restrict__ h,
                                                const float* __restrict__ W1,
                                                const float* __restrict__ b1,
                                                const float* __restrict__ W2,
                                                float* __restrict__ Ai,
                                                float* __restrict__ Aj,
                                                u8* __restrict__ W2q) {
  const int t = threadIdx.x;
  const int bx = blockIdx.x;
  if (bx < 1024) {
    __shared__ float hsh[ND];
    const int i = bx >> 1;
    const int n = (bx & 1) * 256 + t;
    hsh[t] = h[i * ND + t];
    __syncthreads();
    float ai = 0.0f, aj = 0.0f;
#pragma unroll 8
    for (int d = 0; d < ND; ++d) {
      const float hd = hsh[d];
      ai = fmaf(hd, W1[d * NH + n], ai);
      aj = fmaf(hd, W1[(d + ND) * NH + n], aj);
    }
    Ai[i * NH + n] = ai * C2;
    Aj[i * NH + n] = (aj + b1[n]) * C2;
  } else {
    // W2 -> i8 (scale 0.25/127), MFMA B-frag order for i8 32x32x32:
    // frag id g = ks*1024 + nt*64 + lane (16 B): byte j = q(W2[ks*32 + (lane>>5)*16 + j][nt*32 + (lane&31)])
    const int g = (bx - 1024) * 256 + t;  // 0..16383
    const int lane = g & 63;
    const int nt = (g >> 6) & 15;
    const int ks = g >> 10;
    const int n = nt * 32 + (lane & 31);
    const int kb = ks * 32 + ((lane >> 5) << 4);
    u32 w[4];
#pragma unroll
    for (int q = 0; q < 4; ++q) {
      u32 acc = 0;
#pragma unroll
      for (int j = 0; j < 4; ++j) {
        const float wv = fminf(fmaxf(W2[(kb + q * 4 + j) * NH + n], -0.25f), 0.25f);
        const int qi = (int)rintf(wv * 508.0f);  // 508 = 127/0.25
        acc |= ((u32)(qi & 255)) << (8 * j);
      }
      w[q] = acc;
    }
    ((uint4*)W2q)[g] = make_uint4(w[0], w[1], w[2], w[3]);
  }
}

// ---------------- main: i8 pairwise tanh-MLP; M=32 tile, 512 thr / 8 waves, acc=32/lane ----------------
// Block: one i, 32 j's (M=32), N=512, K=512 (16 ks-steps of 32). Wave w: 2 n-tiles nt = w*2+{0,1}.
// X LDS: 16-B slot idx = s*32 + row, s = k>>4; byte j of slot = i8(127*tanh(X[row][s*16+j])).
// A frag (ks): i32x4 at idx ks*64 + (lane>>5)*32 + (lane&31).
// B frag (ks,ntl): uint4 at W2q frag id ks*1024 + (w*2+ntl)*64 + lane.
// __launch_bounds__(512,8): combined VGPR+AGPR <= 64. To make that feasible without spill:
//   (a) acc zero-init AFTER staging (staging's ~40 live VGPRs don't overlap the 32 AGPRs),
//   (b) B-prefetch depth 1 via SSA ping-pong (K-loop live ~= 8 A + 16 B + addrs + 32 acc ~= 62).
__global__ __launch_bounds__(512, 8) void pair_main(const float* __restrict__ Ai,
                                                    const float* __restrict__ Aj,
                                                    const u8* __restrict__ W2q,
                                                    const float* __restrict__ b2,
                                                    const float* __restrict__ W3,
                                                    const float* __restrict__ b3,
                                                    float* __restrict__ out) {
  __shared__ __align__(16) u8 xs[32 * 512];  // 16 KB
  __shared__ float red[8][32];               // 1 KB

  const int t = threadIdx.x;
  const int w = t >> 6;
  const int lane = t & 63;
  const int lhi = lane >> 5;
  const int llo = lane & 31;
  const int bx = blockIdx.x;
  const int i = bx >> 4;
  const int j0 = (bx & 15) * 32;

  // ---- stage X: thread t -> row = t&31, slots s in {t>>5, (t>>5)+16} (16 k's each) ----
  {
    const int row = t & 31;
    const int s0 = t >> 5;  // 0..15
    const float* ajr = Aj + (size_t)(j0 + row) * NH;
    const float* air = Ai + (size_t)i * NH;
#pragma unroll
    for (int uu = 0; uu < 2; ++uu) {
      const int s = s0 + uu * 16;
      const int k0 = s * 16;
      u32 wds[4];
#pragma unroll
      for (int q = 0; q < 4; ++q) {
        const float4 fa = *(const float4*)(ajr + k0 + q * 4);
        const float4 ga = *(const float4*)(air + k0 + q * 4);
        const u32 m0 = tanh_q127_magic(fa.x + ga.x);
        const u32 m1 = tanh_q127_magic(fa.y + ga.y);
        const u32 m2 = tanh_q127_magic(fa.z + ga.z);
        const u32 m3 = tanh_q127_magic(fa.w + ga.w);
        const u32 p01 = perm_b32(m1, m0, 0x0C0C0400u);
        const u32 p23 = perm_b32(m3, m2, 0x0C0C0400u);
        wds[q] = perm_b32(p23, p01, 0x05040100u);
      }
      ((uint4*)xs)[s * 32 + row] = make_uint4(wds[0], wds[1], wds[2], wds[3]);
    }
  }
  __syncthreads();  // only block-wide barrier before epilogue

  // ---- acc init AFTER staging: keeps staging register pressure off the AGPR window ----
  i32x16 acc[2];
#pragma unroll
  for (int nt = 0; nt < 2; ++nt)
#pragma unroll
    for (int q = 0; q < 16; ++q) acc[nt][q] = 0;

  // ---- K-loop: ping-pong x2 unroll, SSA register sets, prefetch distance 1, no barriers ----
  const i32x4* xsv = (const i32x4*)xs;
  const int abase = lhi * 32 + llo;                        // + ks*64
  const uint4* w2v = (const uint4*)W2q + w * 128 + lane;   // + ks*1024, +64 for ntl=1

  i32x4 aE = xsv[abase];
  uint4 bE0 = w2v[0], bE1 = w2v[64];

#pragma unroll
  for (int kk = 0; kk < 8; ++kk) {
    const int ks0 = 2 * kk;
    // prefetch odd step (ks0+1), then consume even
    i32x4 aO = xsv[(ks0 + 1) * 64 + abase];
    const uint4* wpO = w2v + (ks0 + 1) * 1024;
    uint4 bO0 = wpO[0];
    uint4 bO1 = wpO[64];
    acc[0] = __builtin_amdgcn_mfma_i32_32x32x32_i8(aE, __builtin_bit_cast(i32x4, bE0), acc[0], 0, 0, 0);
    acc[1] = __builtin_amdgcn_mfma_i32_32x32x32_i8(aE, __builtin_bit_cast(i32x4, bE1), acc[1], 0, 0, 0);
    // prefetch next even step (ks0+2), then consume odd
    if (kk < 7) {
      aE = xsv[(ks0 + 2) * 64 + abase];
      const uint4* wpE = w2v + (ks0 + 2) * 1024;
      bE0 = wpE[0];
      bE1 = wpE[64];
    }
    acc[0] = __builtin_amdgcn_mfma_i32_32x32x32_i8(aO, __builtin_bit_cast(i32x4, bO0), acc[0], 0, 0, 0);
    acc[1] = __builtin_amdgcn_mfma_i32_32x32x32_i8(aO, __builtin_bit_cast(i32x4, bO1), acc[1], 0, 0, 0);
  }

  // ---- epilogue: y = acc*SCALE + b2*C2; r = 1/(exp2(y)+1); partial = Σw3 - 2 Σ w3·r ----
  const float SCALE = (0.25f / (127.0f * 127.0f)) * C2;
  float b2c[2], w3v[2];
#pragma unroll
  for (int ntl = 0; ntl < 2; ++ntl) {
    const int n = w * 64 + ntl * 32 + llo;
    b2c[ntl] = b2[n] * C2;
    w3v[ntl] = W3[n];
  }
  float w3s = w3v[0] + w3v[1];
#pragma unroll
  for (int off = 1; off < 32; off <<= 1) w3s += __shfl_xor(w3s, off, 64);  // Σ w3 over wave's 64 n

#pragma unroll
  for (int reg = 0; reg < 16; ++reg) {
    float sr = 0.0f;
#pragma unroll
    for (int ntl = 0; ntl < 2; ++ntl) {
      const float y = fmaf((float)acc[ntl][reg], SCALE, b2c[ntl]);
      const float r = rcp_fast(exp2_fast(y) + 1.0f);
      sr = fmaf(w3v[ntl], r, sr);
    }
#pragma unroll
    for (int off = 1; off < 32; off <<= 1) sr += __shfl_xor(sr, off, 64);
    const int row = (reg & 3) + 8 * (reg >> 2) + 4 * lhi;  // 0..31
    if (llo == reg) red[w][row] = fmaf(-2.0f, sr, w3s);
  }
  __syncthreads();
  if (t < 32) {
    float v = b3[0];
#pragma unroll
    for (int ww = 0; ww < 8; ++ww) v += red[ww][t];
    const int j = j0 + t;
    out[i * NB + j] = (j == i) ? -20.0f : v;
  }
}

extern "C" void kernel_launch(void* const* d_in, const int* in_sizes, int n_in,
                              void* d_out, int out_size, void* d_ws, size_t ws_size,
                              hipStream_t stream) {
  const float* h = (const float*)d_in[0];
  const float* W1 = (const float*)d_in[1];
  const float* b1 = (const float*)d_in[2];
  const float* W2 = (const float*)d_in[3];
  const float* b2 = (const float*)d_in[4];
  const float* W3 = (const float*)d_in[5];
  const float* b3 = (const float*)d_in[6];
  float* out = (float*)d_out;

  float* Ai = (float*)d_ws;
  float* Aj = Ai + NB * NH;
  u8* W2q = (u8*)(Aj + NB * NH);

  prep_all<<<1088, 256, 0, stream>>>(h, W1, b1, W2, Ai, Aj, W2q);
  pair_main<<<8192, 512, 0, stream>>>(Ai, Aj, W2q, b2, W3, b3, out);
}